// Round 8
// baseline (621.710 us; speedup 1.0000x reference)
//
#include <hip/hip_runtime.h>
#include <hip/hip_bf16.h>

#define B_ 2
#define N_ 2048
#define FIN 512
#define H_ 8
#define DH 64
#define HD 512 /* H_*DH */
#define SLOPE 0.2f
#define NCHUNK 128
#define CH 16
#define REP 16  // DIAGNOSTIC: per-kernel repeat to expose per-kernel cost in profile

typedef __attribute__((ext_vector_type(8))) short short8;
typedef __attribute__((ext_vector_type(4))) float f32x4;
typedef unsigned short ushort_t;

__device__ __forceinline__ unsigned int sortable_f32(float f) {
  const unsigned int u = __float_as_uint(f);
  return u ^ ((((int)u) >> 31) | 0x80000000u);
}

#define GLOAD_LDS(gp, lp)                                                   \
  __builtin_amdgcn_global_load_lds(                                         \
      (const __attribute__((address_space(1))) void*)(gp),                  \
      (__attribute__((address_space(3))) void*)(lp), 16, 0, 0)

// K0: fused convert (x REP diagnostic)
__global__ __launch_bounds__(256) void k_cvt(const float* __restrict__ f,
                                             const float* __restrict__ W,
                                             ushort_t* __restrict__ fh,
                                             ushort_t* __restrict__ fl,
                                             ushort_t* __restrict__ Bth,
                                             ushort_t* __restrict__ Btl) {
  __shared__ float T[64][65];
  for (int rep_ = 0; rep_ < REP; ++rep_) {
    if (blockIdx.x < 2048) {
      const int i = (blockIdx.x * 256 + threadIdx.x) * 4;
      const float4 v = *(const float4*)(f + i);
      const float vv[4] = {v.x, v.y, v.z, v.w};
      ushort_t hh[4], ll[4];
#pragma unroll
      for (int j = 0; j < 4; ++j) {
        const float x = vv[j];
        const __hip_bfloat16 hb = __float2bfloat16(x);
        const float hf = __bfloat162float(hb);
        const __hip_bfloat16 lb = __float2bfloat16(x - hf);
        hh[j] = *(const ushort_t*)&hb;
        ll[j] = *(const ushort_t*)&lb;
      }
      ushort4 ho, lo;
      ho.x = hh[0]; ho.y = hh[1]; ho.z = hh[2]; ho.w = hh[3];
      lo.x = ll[0]; lo.y = ll[1]; lo.z = ll[2]; lo.w = ll[3];
      *(ushort4*)(fh + i) = ho;
      *(ushort4*)(fl + i) = lo;
    } else {
      const int bid = blockIdx.x - 2048;
      const int k0 = (bid & 7) * 64;
      const int n0 = (bid >> 3) * 64;
      const int tx = threadIdx.x & 63, ty = threadIdx.x >> 6;
#pragma unroll
      for (int p = 0; p < 16; ++p) {
        const int kr = p * 4 + ty;
        T[kr][tx] = W[(k0 + kr) * HD + n0 + tx];
      }
      __syncthreads();
#pragma unroll
      for (int p = 0; p < 16; ++p) {
        const int nr = p * 4 + ty;
        const float x = T[tx][nr];
        const __hip_bfloat16 hb = __float2bfloat16(x);
        const float hf = __bfloat162float(hb);
        const __hip_bfloat16 lb = __float2bfloat16(x - hf);
        Bth[(n0 + nr) * FIN + k0 + tx] = *(const ushort_t*)&hb;
        Btl[(n0 + nr) * FIN + k0 + tx] = *(const ushort_t*)&lb;
      }
      __syncthreads();
    }
  }
}

// K1: GEMM (x REP diagnostic)
__global__ __launch_bounds__(512) void k_gemm_mfma(
    const ushort_t* __restrict__ Ah, const ushort_t* __restrict__ Al,
    const ushort_t* __restrict__ Bth, const ushort_t* __restrict__ Btl,
    const float* __restrict__ aw, float* __restrict__ C,
    float* __restrict__ sl, float* __restrict__ sr) {
  __shared__ ushort_t lA[2][2][128 * 64];
  __shared__ ushort_t lB[2][2][64 * 64];
  __shared__ float slp[2][128], srp[2][128];
  const int tid = threadIdx.x;
  const int lane = tid & 63;
  const int wave = tid >> 6;
  const int row0 = blockIdx.x * 128;
  const int col0 = blockIdx.y * 64;
  const int wm = (wave >> 1) * 32;
  const int wn = (wave & 1) * 32;
  for (int rep_ = 0; rep_ < REP; ++rep_) {
    f32x4 acc[2][2] = {};

#define STAGE(buf, k0)                                                      \
  {                                                                         \
    _Pragma("unroll") for (int p = 0; p < 2; ++p) {                         \
      const int q = p * 512 + tid;                                          \
      const int r = q >> 3, s = q & 7;                                      \
      const int gk = (k0) + ((s ^ (r & 7)) << 3);                           \
      GLOAD_LDS(Ah + (row0 + r) * FIN + gk, &lA[buf][0][q * 8]);            \
      GLOAD_LDS(Al + (row0 + r) * FIN + gk, &lA[buf][1][q * 8]);            \
    }                                                                       \
    {                                                                       \
      const int q = tid;                                                    \
      const int r = q >> 3, s = q & 7;                                      \
      const int gk = (k0) + ((s ^ (r & 7)) << 3);                           \
      GLOAD_LDS(Bth + (col0 + r) * FIN + gk, &lB[buf][0][q * 8]);           \
      GLOAD_LDS(Btl + (col0 + r) * FIN + gk, &lB[buf][1][q * 8]);           \
    }                                                                       \
  }

    STAGE(0, 0);
    __syncthreads();
    int cur = 0;
    for (int t = 0; t < 8; ++t) {
      if (t + 1 < 8) STAGE(cur ^ 1, (t + 1) * 64);
#pragma unroll
      for (int kk = 0; kk < 2; ++kk) {
        short8 a_h[2], a_l[2], b_h[2], b_l[2];
        const int kbyte = kk * 64 + ((lane >> 4) << 4);
#pragma unroll
        for (int fm = 0; fm < 2; ++fm) {
          const int row = wm + fm * 16 + (lane & 15);
          const int off = (row * 128 + (kbyte ^ ((row & 7) << 4))) >> 1;
          a_h[fm] = *(const short8*)&lA[cur][0][off];
          a_l[fm] = *(const short8*)&lA[cur][1][off];
        }
#pragma unroll
        for (int fn = 0; fn < 2; ++fn) {
          const int nn = wn + fn * 16 + (lane & 15);
          const int off = (nn * 128 + (kbyte ^ ((nn & 7) << 4))) >> 1;
          b_h[fn] = *(const short8*)&lB[cur][0][off];
          b_l[fn] = *(const short8*)&lB[cur][1][off];
        }
#pragma unroll
        for (int fm = 0; fm < 2; ++fm)
#pragma unroll
          for (int fn = 0; fn < 2; ++fn) {
            acc[fm][fn] = __builtin_amdgcn_mfma_f32_16x16x32_bf16(
                a_h[fm], b_h[fn], acc[fm][fn], 0, 0, 0);
            acc[fm][fn] = __builtin_amdgcn_mfma_f32_16x16x32_bf16(
                a_h[fm], b_l[fn], acc[fm][fn], 0, 0, 0);
            acc[fm][fn] = __builtin_amdgcn_mfma_f32_16x16x32_bf16(
                a_l[fm], b_h[fn], acc[fm][fn], 0, 0, 0);
          }
      }
      __syncthreads();
      cur ^= 1;
    }
#undef STAGE

#pragma unroll
    for (int fm = 0; fm < 2; ++fm)
#pragma unroll
      for (int fn = 0; fn < 2; ++fn)
#pragma unroll
        for (int r = 0; r < 4; ++r) {
          const int row = row0 + wm + fm * 16 + ((lane >> 4) << 2) + r;
          const int col = col0 + wn + fn * 16 + (lane & 15);
          C[row * HD + col] = acc[fm][fn][r];
        }

    const float al0 = aw[wn + (lane & 15)];
    const float al1 = aw[wn + 16 + (lane & 15)];
    const float ar0 = aw[DH + wn + (lane & 15)];
    const float ar1 = aw[DH + wn + 16 + (lane & 15)];
#pragma unroll
    for (int fm = 0; fm < 2; ++fm)
#pragma unroll
      for (int r = 0; r < 4; ++r) {
        float vsl = acc[fm][0][r] * al0 + acc[fm][1][r] * al1;
        float vsr = acc[fm][0][r] * ar0 + acc[fm][1][r] * ar1;
#pragma unroll
        for (int off = 1; off < 16; off <<= 1) {
          vsl += __shfl_xor(vsl, off, 64);
          vsr += __shfl_xor(vsr, off, 64);
        }
        if ((lane & 15) == 0) {
          const int rr = wm + fm * 16 + ((lane >> 4) << 2) + r;
          slp[wn >> 5][rr] = vsl;
          srp[wn >> 5][rr] = vsr;
        }
      }
    __syncthreads();
    if (tid < 128) {
      const int grow = row0 + tid;
      const int b = grow >> 11, n = grow & (N_ - 1);
      const int h = blockIdx.y;
      sl[(b * H_ + h) * N_ + n] = slp[0][tid] + slp[1][tid];
      sr[(b * H_ + h) * N_ + n] = srp[0][tid] + srp[1][tid];
    }
    __syncthreads();
  }
}

// K2: counting sort + split (x REP diagnostic)
__global__ __launch_bounds__(1024) void k_csort(const float* __restrict__ sr,
                                                const float* __restrict__ sl,
                                                float* __restrict__ sv,
                                                int* __restrict__ si,
                                                int* __restrict__ parr) {
  __shared__ unsigned skey[N_];
  __shared__ int hist[N_];
  __shared__ int sbase[N_];
  __shared__ int cursor[N_];
  __shared__ unsigned tsk[N_];
  __shared__ int tsi[N_];
  __shared__ unsigned redmn[16], redmx[16];
  __shared__ int wtot[16], wexc[16];
  const int base = blockIdx.x * N_;
  const int tid = threadIdx.x;
  const int lane = tid & 63;
  const int wv = tid >> 6;
  for (int rep_ = 0; rep_ < REP; ++rep_) {
    const unsigned k0v = sortable_f32(sr[base + tid]);
    const unsigned k1v = sortable_f32(sr[base + tid + 1024]);
    skey[tid] = k0v;
    skey[tid + 1024] = k1v;
    hist[tid] = 0;
    hist[tid + 1024] = 0;
    unsigned mn = k0v < k1v ? k0v : k1v;
    unsigned mx = k0v > k1v ? k0v : k1v;
#pragma unroll
    for (int off = 32; off > 0; off >>= 1) {
      const unsigned omn = __shfl_xor(mn, off, 64);
      const unsigned omx = __shfl_xor(mx, off, 64);
      mn = omn < mn ? omn : mn;
      mx = omx > mx ? omx : mx;
    }
    if (lane == 0) { redmn[wv] = mn; redmx[wv] = mx; }
    __syncthreads();
    if (tid == 0) {
      unsigned m1 = redmn[0], m2 = redmx[0];
#pragma unroll
      for (int w = 1; w < 16; ++w) {
        m1 = redmn[w] < m1 ? redmn[w] : m1;
        m2 = redmx[w] > m2 ? redmx[w] : m2;
      }
      redmn[0] = m1; redmx[0] = m2;
    }
    __syncthreads();
    const unsigned kmin = redmn[0];
    const unsigned range = redmx[0] - kmin;
    const float scalef = range ? 2047.0f / (float)range : 0.0f;
#define BUCKET(k)                                                            \
  ({ int b_ = (int)((float)((k) - kmin) * scalef); b_ > 2047 ? 2047 : b_; })
    atomicAdd(&hist[BUCKET(k0v)], 1);
    atomicAdd(&hist[BUCKET(k1v)], 1);
    __syncthreads();
    {
      const int e0 = hist[wv * 128 + lane];
      const int e1 = hist[wv * 128 + 64 + lane];
      int s0 = e0, s1 = e1;
#pragma unroll
      for (int off = 1; off < 64; off <<= 1) {
        const int o0 = __shfl_up(s0, off, 64);
        const int o1 = __shfl_up(s1, off, 64);
        if (lane >= off) { s0 += o0; s1 += o1; }
      }
      const int tot0 = __shfl(s0, 63, 64);
      s1 += tot0;
      sbase[wv * 128 + lane] = s0 - e0;
      sbase[wv * 128 + 64 + lane] = s1 - e1;
      if (lane == 63) wtot[wv] = s1;
    }
    __syncthreads();
    if (tid == 0) {
      int r = 0;
#pragma unroll
      for (int w = 0; w < 16; ++w) { wexc[w] = r; r += wtot[w]; }
    }
    __syncthreads();
    {
      const int a0 = sbase[tid] + wexc[tid >> 7];
      const int a1 = sbase[tid + 1024] + wexc[(tid + 1024) >> 7];
      sbase[tid] = a0;
      sbase[tid + 1024] = a1;
      cursor[tid] = a0;
      cursor[tid + 1024] = a1;
    }
    __syncthreads();
    {
      const int b0 = BUCKET(k0v);
      const int p0 = atomicAdd(&cursor[b0], 1);
      tsk[p0] = k0v; tsi[p0] = tid;
      const int b1 = BUCKET(k1v);
      const int p1 = atomicAdd(&cursor[b1], 1);
      tsk[p1] = k1v; tsi[p1] = tid + 1024;
    }
    __syncthreads();
#pragma unroll
    for (int e = 0; e < 2; ++e) {
      const int s = tid + e * 1024;
      const unsigned k = tsk[s];
      const int i = tsi[s];
      const int b = BUCKET(k);
      const int lo = sbase[b];
      const int cnt = hist[b];
      int r = 0;
      for (int t2 = lo; t2 < lo + cnt; ++t2) {
        const unsigned kt = tsk[t2];
        r += (kt < k || (kt == k && tsi[t2] < i)) ? 1 : 0;
      }
      const int pos = lo + r;
      const unsigned u = k;
      const unsigned fbits = (u & 0x80000000u) ? (u ^ 0x80000000u) : ~u;
      sv[base + pos] = __uint_as_float(fbits);
      si[base + pos] = i;
      skey[pos] = k;
    }
    __syncthreads();
#pragma unroll
    for (int e = 0; e < 2; ++e) {
      const int i2 = tid + e * 1024;
      const unsigned th = sortable_f32(-sl[base + i2]);
      int lo = 0, hi = N_;
      while (lo < hi) {
        const int mid = (lo + hi) >> 1;
        if (skey[mid] < th) lo = mid + 1; else hi = mid;
      }
      parr[base + i2] = lo;
    }
#undef BUCKET
    __syncthreads();
  }
}

// K4: chunk prefixes (x REP diagnostic)
__global__ __launch_bounds__(64) void k_chunks(const float* __restrict__ g,
                                               const float* __restrict__ sv,
                                               const int* __restrict__ si,
                                               float* __restrict__ P1,
                                               float* __restrict__ P2,
                                               float* __restrict__ Zpe1,
                                               float* __restrict__ Zpe2,
                                               float* __restrict__ C1,
                                               float* __restrict__ C2,
                                               float* __restrict__ Zc1,
                                               float* __restrict__ Zc2) {
  const int bh = blockIdx.x >> 7;
  const int c = blockIdx.x & 127;
  const int b = bh >> 3, h = bh & 7;
  const int lane = threadIdx.x;
  const int base = bh * N_;
  for (int rep_ = 0; rep_ < REP; ++rep_) {
    const int t = c * CH + (lane & 15);
    const float m = sv[base + N_ - 1];
    const float val = sv[base + t];
    const float e1 = __expf(val - m);
    const float e2 = __expf(SLOPE * (val - m));
    const int jv = si[base + t];
    float s1 = e1, s2 = e2;
#pragma unroll
    for (int off = 1; off < 16; off <<= 1) {
      const float o1 = __shfl_up(s1, off, 16);
      const float o2 = __shfl_up(s2, off, 16);
      if ((lane & 15) >= off) { s1 += o1; s2 += o2; }
    }
    if (lane < 16) {
      Zpe1[base + t] = s1 - e1;
      Zpe2[base + t] = s2 - e2;
    }
    if (lane == 15) { Zc1[blockIdx.x] = s1; Zc2[blockIdx.x] = s2; }
    float acc1 = 0.f, acc2 = 0.f;
#pragma unroll
    for (int u = 0; u < CH; ++u) {
      P1[(base + c * CH + u) * 64 + lane] = acc1;
      P2[(base + c * CH + u) * 64 + lane] = acc2;
      const float wa = __shfl(e1, u, 64);
      const float wb = __shfl(e2, u, 64);
      const int j = __shfl(jv, u, 64);
      const float gv = g[(b * N_ + j) * HD + h * DH + lane];
      acc1 = fmaf(wa, gv, acc1);
      acc2 = fmaf(wb, gv, acc2);
    }
    C1[blockIdx.x * 64 + lane] = acc1;
    C2[blockIdx.x * 64 + lane] = acc2;
  }
}

// K5: scan (x REP diagnostic)
__global__ __launch_bounds__(64) void k_scan(const float* __restrict__ C1,
                                             const float* __restrict__ C2,
                                             const float* __restrict__ Zc1,
                                             const float* __restrict__ Zc2,
                                             float* __restrict__ U1,
                                             float* __restrict__ U2,
                                             float* __restrict__ Zb1,
                                             float* __restrict__ Zb2) {
  const int bh = blockIdx.x;
  const int d = threadIdx.x;
  for (int rep_ = 0; rep_ < REP; ++rep_) {
    float r1 = 0.f, r2 = 0.f;
#pragma unroll 8
    for (int c = 0; c < NCHUNK; ++c) {
      U1[(bh * 129 + c) * 64 + d] = r1;
      U2[(bh * 129 + c) * 64 + d] = r2;
      r1 += C1[(bh * NCHUNK + c) * 64 + d];
      r2 += C2[(bh * NCHUNK + c) * 64 + d];
    }
    U1[(bh * 129 + NCHUNK) * 64 + d] = r1;
    U2[(bh * 129 + NCHUNK) * 64 + d] = r2;
    if (d == 0) {
      float z1 = 0.f, z2 = 0.f;
#pragma unroll 8
      for (int c = 0; c < NCHUNK; ++c) {
        Zb1[bh * 129 + c] = z1;
        Zb2[bh * 129 + c] = z2;
        z1 += Zc1[bh * NCHUNK + c];
        z2 += Zc2[bh * NCHUNK + c];
      }
      Zb1[bh * 129 + NCHUNK] = z1;
      Zb2[bh * 129 + NCHUNK] = z2;
    }
  }
}

// K6: output combine (x REP diagnostic)
__global__ __launch_bounds__(256) void k_out(const float* __restrict__ sl,
                                             const float* __restrict__ sv,
                                             const int* __restrict__ parr,
                                             const float* __restrict__ P1,
                                             const float* __restrict__ P2,
                                             const float* __restrict__ Zpe1,
                                             const float* __restrict__ Zpe2,
                                             const float* __restrict__ U1,
                                             const float* __restrict__ U2,
                                             const float* __restrict__ Zb1,
                                             const float* __restrict__ Zb2,
                                             float* __restrict__ out) {
  const int wv = blockIdx.x * 4 + (threadIdx.x >> 6);
  const int d = threadIdx.x & 63;
  const int h = wv & 7;
  const int row = wv >> 3;
  const int b = row >> 11;
  const int i = row & (N_ - 1);
  const int bh = b * H_ + h;
  const int base = bh * N_;
  for (int rep_ = 0; rep_ < REP; ++rep_) {
    const float sli = sl[base + i];
    const float m = sv[base + N_ - 1];
    const int p = parr[base + i];
    const float slm = sli + m;
    const float M = slm >= 0.f ? slm : SLOPE * slm;
    const float c1 = __expf(slm - M);
    const float c2 = __expf(SLOPE * slm - M);
    const int c = p >> 4;
    const float tot1 = U1[(bh * 129 + NCHUNK) * 64 + d];
    const float b1 = U1[(bh * 129 + c) * 64 + d];
    const float b2 = U2[(bh * 129 + c) * 64 + d];
    const float zt1 = Zb1[bh * 129 + NCHUNK];
    const float zb1 = Zb1[bh * 129 + c];
    const float zb2 = Zb2[bh * 129 + c];
    float p1 = 0.f, p2 = 0.f, zp1 = 0.f, zp2 = 0.f;
    if (p < N_) {
      p1 = P1[(base + p) * 64 + d];
      p2 = P2[(base + p) * 64 + d];
      zp1 = Zpe1[base + p];
      zp2 = Zpe2[base + p];
    }
    const float S1 = tot1 - b1 - p1;
    const float P2v = b2 + p2;
    const float Z = c1 * (zt1 - zb1 - zp1) + c2 * (zb2 + zp2);
    out[row * HD + h * DH + d] = (c1 * S1 + c2 * P2v) / Z;
  }
}

extern "C" void kernel_launch(void* const* d_in, const int* in_sizes, int n_in,
                              void* d_out, int out_size, void* d_ws, size_t ws_size,
                              hipStream_t stream) {
  const float* f = (const float*)d_in[0];
  const float* W = (const float*)d_in[2];
  const float* aw = (const float*)d_in[3];
  float* out = (float*)d_out;

  float* g = (float*)d_ws;
  float* sl = g + B_ * N_ * HD;
  float* sr = sl + B_ * N_ * H_;
  float* sv = sr + B_ * N_ * H_;
  int* si = (int*)(sv + B_ * N_ * H_);
  float* P1 = (float*)(si + B_ * N_ * H_);
  float* P2 = P1 + B_ * H_ * N_ * 64;
  float* Zpe1 = P2 + B_ * H_ * N_ * 64;
  float* Zpe2 = Zpe1 + B_ * N_ * H_;
  float* U1 = Zpe2 + B_ * N_ * H_;
  float* U2 = U1 + 16 * 129 * 64;
  float* Zb1 = U2 + 16 * 129 * 64;
  float* Zb2 = Zb1 + 16 * 129;
  float* C1 = Zb2 + 16 * 129;
  float* C2 = C1 + 16 * NCHUNK * 64;
  float* Zc1 = C2 + 16 * NCHUNK * 64;
  float* Zc2 = Zc1 + 16 * NCHUNK;
  int* parr = (int*)(Zc2 + 16 * NCHUNK);

  ushort_t* fh = (ushort_t*)P1;
  ushort_t* fl = fh + 4096 * FIN;
  ushort_t* Bth = (ushort_t*)P2;
  ushort_t* Btl = Bth + HD * FIN;

  hipLaunchKernelGGL(k_cvt, dim3(2048 + 64), dim3(256), 0, stream, f, W, fh, fl, Bth, Btl);
  hipLaunchKernelGGL(k_gemm_mfma, dim3((B_ * N_) / 128, HD / 64), dim3(512), 0, stream,
                     fh, fl, Bth, Btl, aw, g, sl, sr);
  hipLaunchKernelGGL(k_csort, dim3(B_ * H_), dim3(1024), 0, stream, sr, sl, sv, si, parr);
  hipLaunchKernelGGL(k_chunks, dim3(B_ * H_ * NCHUNK), dim3(64), 0, stream, g, sv, si,
                     P1, P2, Zpe1, Zpe2, C1, C2, Zc1, Zc2);
  hipLaunchKernelGGL(k_scan, dim3(B_ * H_), dim3(64), 0, stream, C1, C2, Zc1, Zc2, U1, U2, Zb1, Zb2);
  hipLaunchKernelGGL(k_out, dim3(B_ * N_ * H_ / 4), dim3(256), 0, stream,
                     sl, sv, parr, P1, P2, Zpe1, Zpe2, U1, U2, Zb1, Zb2, out);
}

// Round 9
// 63.523 us; speedup vs baseline: 9.7872x; 9.7872x over previous
//
#include <hip/hip_runtime.h>
#include <hip/hip_bf16.h>

#define B_ 2
#define N_ 2048
#define FIN 512
#define H_ 8
#define DH 64
#define HD 512 /* H_*DH */
#define SLOPE 0.2f
#define NCHUNK 128
#define CH 16

typedef __attribute__((ext_vector_type(8))) short short8;
typedef __attribute__((ext_vector_type(4))) float f32x4;
typedef unsigned short ushort_t;

#define GLOAD_LDS(gp, lp)                                                   \
  __builtin_amdgcn_global_load_lds(                                         \
      (const __attribute__((address_space(1))) void*)(gp),                  \
      (__attribute__((address_space(3))) void*)(lp), 16, 0, 0)

// K0: fused convert: blocks [0,2048) split f into bf16 hi/lo; blocks
// [2048,2112) transpose W -> Wt and split into bf16 hi/lo.
__global__ __launch_bounds__(256) void k_cvt(const float* __restrict__ f,
                                             const float* __restrict__ W,
                                             ushort_t* __restrict__ fh,
                                             ushort_t* __restrict__ fl,
                                             ushort_t* __restrict__ Bth,
                                             ushort_t* __restrict__ Btl) {
  __shared__ float T[64][65];
  if (blockIdx.x < 2048) {
    const int i = (blockIdx.x * 256 + threadIdx.x) * 4;
    const float4 v = *(const float4*)(f + i);
    const float vv[4] = {v.x, v.y, v.z, v.w};
    ushort_t hh[4], ll[4];
#pragma unroll
    for (int j = 0; j < 4; ++j) {
      const float x = vv[j];
      const __hip_bfloat16 hb = __float2bfloat16(x);
      const float hf = __bfloat162float(hb);
      const __hip_bfloat16 lb = __float2bfloat16(x - hf);
      hh[j] = *(const ushort_t*)&hb;
      ll[j] = *(const ushort_t*)&lb;
    }
    ushort4 ho, lo;
    ho.x = hh[0]; ho.y = hh[1]; ho.z = hh[2]; ho.w = hh[3];
    lo.x = ll[0]; lo.y = ll[1]; lo.z = ll[2]; lo.w = ll[3];
    *(ushort4*)(fh + i) = ho;
    *(ushort4*)(fl + i) = lo;
  } else {
    const int bid = blockIdx.x - 2048;
    const int k0 = (bid & 7) * 64;
    const int n0 = (bid >> 3) * 64;
    const int tx = threadIdx.x & 63, ty = threadIdx.x >> 6;
#pragma unroll
    for (int p = 0; p < 16; ++p) {
      const int kr = p * 4 + ty;
      T[kr][tx] = W[(k0 + kr) * HD + n0 + tx];
    }
    __syncthreads();
#pragma unroll
    for (int p = 0; p < 16; ++p) {
      const int nr = p * 4 + ty;
      const float x = T[tx][nr];
      const __hip_bfloat16 hb = __float2bfloat16(x);
      const float hf = __bfloat162float(hb);
      const __hip_bfloat16 lb = __float2bfloat16(x - hf);
      Bth[(n0 + nr) * FIN + k0 + tx] = *(const ushort_t*)&hb;
      Btl[(n0 + nr) * FIN + k0 + tx] = *(const ushort_t*)&lb;
    }
  }
}

// K1: g = f @ W via bf16 MFMA split precision (ah*bh + ah*bl + al*bh).
// BM=128, BN=64, BK=64, 512 threads (8 waves), dbuf prefetch.
// Fused sl/sr epilogue (col tile == head).
__global__ __launch_bounds__(512) void k_gemm_mfma(
    const ushort_t* __restrict__ Ah, const ushort_t* __restrict__ Al,
    const ushort_t* __restrict__ Bth, const ushort_t* __restrict__ Btl,
    const float* __restrict__ aw, float* __restrict__ C,
    float* __restrict__ sl, float* __restrict__ sr) {
  __shared__ ushort_t lA[2][2][128 * 64];
  __shared__ ushort_t lB[2][2][64 * 64];
  __shared__ float slp[2][128], srp[2][128];
  const int tid = threadIdx.x;
  const int lane = tid & 63;
  const int wave = tid >> 6;
  const int row0 = blockIdx.x * 128;
  const int col0 = blockIdx.y * 64;
  const int wm = (wave >> 1) * 32;
  const int wn = (wave & 1) * 32;
  f32x4 acc[2][2] = {};

#define STAGE(buf, k0)                                                      \
  {                                                                         \
    _Pragma("unroll") for (int p = 0; p < 2; ++p) {                         \
      const int q = p * 512 + tid;                                          \
      const int r = q >> 3, s = q & 7;                                      \
      const int gk = (k0) + ((s ^ (r & 7)) << 3);                           \
      GLOAD_LDS(Ah + (row0 + r) * FIN + gk, &lA[buf][0][q * 8]);            \
      GLOAD_LDS(Al + (row0 + r) * FIN + gk, &lA[buf][1][q * 8]);            \
    }                                                                       \
    {                                                                       \
      const int q = tid;                                                    \
      const int r = q >> 3, s = q & 7;                                      \
      const int gk = (k0) + ((s ^ (r & 7)) << 3);                           \
      GLOAD_LDS(Bth + (col0 + r) * FIN + gk, &lB[buf][0][q * 8]);           \
      GLOAD_LDS(Btl + (col0 + r) * FIN + gk, &lB[buf][1][q * 8]);           \
    }                                                                       \
  }

  STAGE(0, 0);
  __syncthreads();
  int cur = 0;
  for (int t = 0; t < 8; ++t) {
    if (t + 1 < 8) STAGE(cur ^ 1, (t + 1) * 64);
#pragma unroll
    for (int kk = 0; kk < 2; ++kk) {
      short8 a_h[2], a_l[2], b_h[2], b_l[2];
      const int kbyte = kk * 64 + ((lane >> 4) << 4);
#pragma unroll
      for (int fm = 0; fm < 2; ++fm) {
        const int row = wm + fm * 16 + (lane & 15);
        const int off = (row * 128 + (kbyte ^ ((row & 7) << 4))) >> 1;
        a_h[fm] = *(const short8*)&lA[cur][0][off];
        a_l[fm] = *(const short8*)&lA[cur][1][off];
      }
#pragma unroll
      for (int fn = 0; fn < 2; ++fn) {
        const int nn = wn + fn * 16 + (lane & 15);
        const int off = (nn * 128 + (kbyte ^ ((nn & 7) << 4))) >> 1;
        b_h[fn] = *(const short8*)&lB[cur][0][off];
        b_l[fn] = *(const short8*)&lB[cur][1][off];
      }
#pragma unroll
      for (int fm = 0; fm < 2; ++fm)
#pragma unroll
        for (int fn = 0; fn < 2; ++fn) {
          acc[fm][fn] = __builtin_amdgcn_mfma_f32_16x16x32_bf16(
              a_h[fm], b_h[fn], acc[fm][fn], 0, 0, 0);
          acc[fm][fn] = __builtin_amdgcn_mfma_f32_16x16x32_bf16(
              a_h[fm], b_l[fn], acc[fm][fn], 0, 0, 0);
          acc[fm][fn] = __builtin_amdgcn_mfma_f32_16x16x32_bf16(
              a_l[fm], b_h[fn], acc[fm][fn], 0, 0, 0);
        }
    }
    __syncthreads();
    cur ^= 1;
  }
#undef STAGE

#pragma unroll
  for (int fm = 0; fm < 2; ++fm)
#pragma unroll
    for (int fn = 0; fn < 2; ++fn)
#pragma unroll
      for (int r = 0; r < 4; ++r) {
        const int row = row0 + wm + fm * 16 + ((lane >> 4) << 2) + r;
        const int col = col0 + wn + fn * 16 + (lane & 15);
        C[row * HD + col] = acc[fm][fn][r];
      }

  const float al0 = aw[wn + (lane & 15)];
  const float al1 = aw[wn + 16 + (lane & 15)];
  const float ar0 = aw[DH + wn + (lane & 15)];
  const float ar1 = aw[DH + wn + 16 + (lane & 15)];
#pragma unroll
  for (int fm = 0; fm < 2; ++fm)
#pragma unroll
    for (int r = 0; r < 4; ++r) {
      float vsl = acc[fm][0][r] * al0 + acc[fm][1][r] * al1;
      float vsr = acc[fm][0][r] * ar0 + acc[fm][1][r] * ar1;
#pragma unroll
      for (int off = 1; off < 16; off <<= 1) {
        vsl += __shfl_xor(vsl, off, 64);
        vsr += __shfl_xor(vsr, off, 64);
      }
      if ((lane & 15) == 0) {
        const int rr = wm + fm * 16 + ((lane >> 4) << 2) + r;
        slp[wn >> 5][rr] = vsl;
        srp[wn >> 5][rr] = vsr;
      }
    }
  __syncthreads();
  if (tid < 128) {
    const int grow = row0 + tid;
    const int b = grow >> 11, n = grow & (N_ - 1);
    const int h = blockIdx.y;
    sl[(b * H_ + h) * N_ + n] = slp[0][tid] + slp[1][tid];
    sr[(b * H_ + h) * N_ + n] = srp[0][tid] + srp[1][tid];
  }
}

// K2: counting sort per (b,h) + fused split search. 16 blocks x 1024 threads.
// VALUE-linear buckets (uniform for ~normal data; key-space bucketing was
// exponent-log and collapsed to ~144 used buckets -> 19us. R8 fix.)
__global__ __launch_bounds__(1024) void k_csort(const float* __restrict__ sr,
                                                const float* __restrict__ sl,
                                                float* __restrict__ sv,
                                                int* __restrict__ si,
                                                int* __restrict__ parr) {
  __shared__ int hist[N_];
  __shared__ int sbase[N_];
  __shared__ int cursor[N_];
  __shared__ float tsv[N_];
  __shared__ int tsi[N_];
  __shared__ float sval[N_];
  __shared__ float redmn[16], redmx[16];
  __shared__ int wtot[16], wexc[16];
  const int base = blockIdx.x * N_;
  const int tid = threadIdx.x;
  const int lane = tid & 63;
  const int wv = tid >> 6;

  const float v0 = sr[base + tid];
  const float v1 = sr[base + tid + 1024];
  hist[tid] = 0;
  hist[tid + 1024] = 0;
  float mn = fminf(v0, v1);
  float mx = fmaxf(v0, v1);
#pragma unroll
  for (int off = 32; off > 0; off >>= 1) {
    mn = fminf(mn, __shfl_xor(mn, off, 64));
    mx = fmaxf(mx, __shfl_xor(mx, off, 64));
  }
  if (lane == 0) { redmn[wv] = mn; redmx[wv] = mx; }
  __syncthreads();
  if (tid == 0) {
    float m1 = redmn[0], m2 = redmx[0];
#pragma unroll
    for (int w = 1; w < 16; ++w) {
      m1 = fminf(m1, redmn[w]);
      m2 = fmaxf(m2, redmx[w]);
    }
    redmn[0] = m1; redmx[0] = m2;
  }
  __syncthreads();
  const float vmin = redmn[0];
  const float range = redmx[0] - vmin;
  const float scalef = range > 0.f ? 2047.0f / range : 0.0f;
#define BUCKET(v)                                                            \
  ({ int b_ = (int)(((v) - vmin) * scalef); b_ > 2047 ? 2047 : b_; })
  // histogram (value-uniform buckets -> light atomic contention)
  atomicAdd(&hist[BUCKET(v0)], 1);
  atomicAdd(&hist[BUCKET(v1)], 1);
  __syncthreads();
  // exclusive scan of hist: wave w scans 128 buckets
  {
    const int e0 = hist[wv * 128 + lane];
    const int e1 = hist[wv * 128 + 64 + lane];
    int s0 = e0, s1 = e1;
#pragma unroll
    for (int off = 1; off < 64; off <<= 1) {
      const int o0 = __shfl_up(s0, off, 64);
      const int o1 = __shfl_up(s1, off, 64);
      if (lane >= off) { s0 += o0; s1 += o1; }
    }
    const int tot0 = __shfl(s0, 63, 64);
    s1 += tot0;
    sbase[wv * 128 + lane] = s0 - e0;
    sbase[wv * 128 + 64 + lane] = s1 - e1;
    if (lane == 63) wtot[wv] = s1;
  }
  __syncthreads();
  if (tid == 0) {
    int r = 0;
#pragma unroll
    for (int w = 0; w < 16; ++w) { wexc[w] = r; r += wtot[w]; }
  }
  __syncthreads();
  {
    const int a0 = sbase[tid] + wexc[tid >> 7];
    const int a1 = sbase[tid + 1024] + wexc[(tid + 1024) >> 7];
    sbase[tid] = a0;
    sbase[tid + 1024] = a1;
    cursor[tid] = a0;
    cursor[tid + 1024] = a1;
  }
  __syncthreads();
  // scatter (arbitrary order within bucket; final rank is deterministic)
  {
    const int b0 = BUCKET(v0);
    const int p0 = atomicAdd(&cursor[b0], 1);
    tsv[p0] = v0; tsi[p0] = tid;
    const int b1 = BUCKET(v1);
    const int p1 = atomicAdd(&cursor[b1], 1);
    tsv[p1] = v1; tsi[p1] = tid + 1024;
  }
  __syncthreads();
  // exact rank within bucket (float order, idx tie-break); emit sorted arrays
#pragma unroll
  for (int e = 0; e < 2; ++e) {
    const int s = tid + e * 1024;
    const float v = tsv[s];
    const int i = tsi[s];
    const int b = BUCKET(v);
    const int lo = sbase[b];
    const int cnt = hist[b];
    int r = 0;
    for (int t2 = lo; t2 < lo + cnt; ++t2) {
      const float vt = tsv[t2];
      r += (vt < v || (vt == v && tsi[t2] < i)) ? 1 : 0;
    }
    const int pos = lo + r;
    sv[base + pos] = v;
    si[base + pos] = i;
    sval[pos] = v;
  }
  __syncthreads();
  // split search: p(i) = #{v_j < -sl_i} (same float order as the sort)
#pragma unroll
  for (int e = 0; e < 2; ++e) {
    const int i2 = tid + e * 1024;
    const float th = -sl[base + i2];
    int lo = 0, hi = N_;
    while (lo < hi) {
      const int mid = (lo + hi) >> 1;
      if (sval[mid] < th) lo = mid + 1; else hi = mid;
    }
    parr[base + i2] = lo;
  }
#undef BUCKET
}

// K4: per (b,h,chunk of 16): element-granular exclusive prefixes of w*g
// (P1/P2) and of scalar weights (Zpe via width-16 shfl scan), chunk totals.
__global__ __launch_bounds__(64) void k_chunks(const float* __restrict__ g,
                                               const float* __restrict__ sv,
                                               const int* __restrict__ si,
                                               float* __restrict__ P1,
                                               float* __restrict__ P2,
                                               float* __restrict__ Zpe1,
                                               float* __restrict__ Zpe2,
                                               float* __restrict__ C1,
                                               float* __restrict__ C2,
                                               float* __restrict__ Zc1,
                                               float* __restrict__ Zc2) {
  const int bh = blockIdx.x >> 7;
  const int c = blockIdx.x & 127;
  const int b = bh >> 3, h = bh & 7;
  const int lane = threadIdx.x;
  const int base = bh * N_;
  const int t = c * CH + (lane & 15);
  const float m = sv[base + N_ - 1];
  const float val = sv[base + t];
  const float e1 = __expf(val - m);
  const float e2 = __expf(SLOPE * (val - m));
  const int jv = si[base + t];
  float s1 = e1, s2 = e2;
#pragma unroll
  for (int off = 1; off < 16; off <<= 1) {
    const float o1 = __shfl_up(s1, off, 16);
    const float o2 = __shfl_up(s2, off, 16);
    if ((lane & 15) >= off) { s1 += o1; s2 += o2; }
  }
  if (lane < 16) {
    Zpe1[base + t] = s1 - e1;
    Zpe2[base + t] = s2 - e2;
  }
  if (lane == 15) { Zc1[blockIdx.x] = s1; Zc2[blockIdx.x] = s2; }
  float acc1 = 0.f, acc2 = 0.f;
#pragma unroll
  for (int u = 0; u < CH; ++u) {
    P1[(base + c * CH + u) * 64 + lane] = acc1;
    P2[(base + c * CH + u) * 64 + lane] = acc2;
    const float wa = __shfl(e1, u, 64);
    const float wb = __shfl(e2, u, 64);
    const int j = __shfl(jv, u, 64);
    const float gv = g[(b * N_ + j) * HD + h * DH + lane];
    acc1 = fmaf(wa, gv, acc1);
    acc2 = fmaf(wb, gv, acc2);
  }
  C1[blockIdx.x * 64 + lane] = acc1;
  C2[blockIdx.x * 64 + lane] = acc2;
}

// K5: exclusive scan of chunk sums (129 entries incl. total), per (b,h)
__global__ __launch_bounds__(64) void k_scan(const float* __restrict__ C1,
                                             const float* __restrict__ C2,
                                             const float* __restrict__ Zc1,
                                             const float* __restrict__ Zc2,
                                             float* __restrict__ U1,
                                             float* __restrict__ U2,
                                             float* __restrict__ Zb1,
                                             float* __restrict__ Zb2) {
  const int bh = blockIdx.x;
  const int d = threadIdx.x;
  float r1 = 0.f, r2 = 0.f;
#pragma unroll 8
  for (int c = 0; c < NCHUNK; ++c) {
    U1[(bh * 129 + c) * 64 + d] = r1;
    U2[(bh * 129 + c) * 64 + d] = r2;
    r1 += C1[(bh * NCHUNK + c) * 64 + d];
    r2 += C2[(bh * NCHUNK + c) * 64 + d];
  }
  U1[(bh * 129 + NCHUNK) * 64 + d] = r1;
  U2[(bh * 129 + NCHUNK) * 64 + d] = r2;
  if (d == 0) {
    float z1 = 0.f, z2 = 0.f;
#pragma unroll 8
    for (int c = 0; c < NCHUNK; ++c) {
      Zb1[bh * 129 + c] = z1;
      Zb2[bh * 129 + c] = z2;
      z1 += Zc1[bh * NCHUNK + c];
      z2 += Zc2[bh * NCHUNK + c];
    }
    Zb1[bh * 129 + NCHUNK] = z1;
    Zb2[bh * 129 + NCHUNK] = z2;
  }
}

// K6: branch-free streaming combine using precomputed split p
__global__ __launch_bounds__(256) void k_out(const float* __restrict__ sl,
                                             const float* __restrict__ sv,
                                             const int* __restrict__ parr,
                                             const float* __restrict__ P1,
                                             const float* __restrict__ P2,
                                             const float* __restrict__ Zpe1,
                                             const float* __restrict__ Zpe2,
                                             const float* __restrict__ U1,
                                             const float* __restrict__ U2,
                                             const float* __restrict__ Zb1,
                                             const float* __restrict__ Zb2,
                                             float* __restrict__ out) {
  const int wv = blockIdx.x * 4 + (threadIdx.x >> 6);
  const int d = threadIdx.x & 63;
  const int h = wv & 7;
  const int row = wv >> 3;
  const int b = row >> 11;
  const int i = row & (N_ - 1);
  const int bh = b * H_ + h;
  const int base = bh * N_;
  const float sli = sl[base + i];
  const float m = sv[base + N_ - 1];
  const int p = parr[base + i];
  const float slm = sli + m;
  const float M = slm >= 0.f ? slm : SLOPE * slm;
  const float c1 = __expf(slm - M);
  const float c2 = __expf(SLOPE * slm - M);
  const int c = p >> 4;
  const float tot1 = U1[(bh * 129 + NCHUNK) * 64 + d];
  const float b1 = U1[(bh * 129 + c) * 64 + d];
  const float b2 = U2[(bh * 129 + c) * 64 + d];
  const float zt1 = Zb1[bh * 129 + NCHUNK];
  const float zb1 = Zb1[bh * 129 + c];
  const float zb2 = Zb2[bh * 129 + c];
  float p1 = 0.f, p2 = 0.f, zp1 = 0.f, zp2 = 0.f;
  if (p < N_) {
    p1 = P1[(base + p) * 64 + d];
    p2 = P2[(base + p) * 64 + d];
    zp1 = Zpe1[base + p];
    zp2 = Zpe2[base + p];
  }
  const float S1 = tot1 - b1 - p1;
  const float P2v = b2 + p2;
  const float Z = c1 * (zt1 - zb1 - zp1) + c2 * (zb2 + zp2);
  out[row * HD + h * DH + d] = (c1 * S1 + c2 * P2v) / Z;
}

extern "C" void kernel_launch(void* const* d_in, const int* in_sizes, int n_in,
                              void* d_out, int out_size, void* d_ws, size_t ws_size,
                              hipStream_t stream) {
  const float* f = (const float*)d_in[0];
  // d_in[1] = adj_mat (all ones, unused by reference math)
  const float* W = (const float*)d_in[2];
  const float* aw = (const float*)d_in[3];
  float* out = (float*)d_out;

  float* g = (float*)d_ws;
  float* sl = g + B_ * N_ * HD;
  float* sr = sl + B_ * N_ * H_;
  float* sv = sr + B_ * N_ * H_;
  int* si = (int*)(sv + B_ * N_ * H_);
  float* P1 = (float*)(si + B_ * N_ * H_);
  float* P2 = P1 + B_ * H_ * N_ * 64;
  float* Zpe1 = P2 + B_ * H_ * N_ * 64;
  float* Zpe2 = Zpe1 + B_ * N_ * H_;
  float* U1 = Zpe2 + B_ * N_ * H_;
  float* U2 = U1 + 16 * 129 * 64;
  float* Zb1 = U2 + 16 * 129 * 64;
  float* Zb2 = Zb1 + 16 * 129;
  float* C1 = Zb2 + 16 * 129;
  float* C2 = C1 + 16 * NCHUNK * 64;
  float* Zc1 = C2 + 16 * NCHUNK * 64;
  float* Zc2 = Zc1 + 16 * NCHUNK;
  int* parr = (int*)(Zc2 + 16 * NCHUNK);

  ushort_t* fh = (ushort_t*)P1;
  ushort_t* fl = fh + 4096 * FIN;
  ushort_t* Bth = (ushort_t*)P2;
  ushort_t* Btl = Bth + HD * FIN;

  hipLaunchKernelGGL(k_cvt, dim3(2048 + 64), dim3(256), 0, stream, f, W, fh, fl, Bth, Btl);
  hipLaunchKernelGGL(k_gemm_mfma, dim3((B_ * N_) / 128, HD / 64), dim3(512), 0, stream,
                     fh, fl, Bth, Btl, aw, g, sl, sr);
  hipLaunchKernelGGL(k_csort, dim3(B_ * H_), dim3(1024), 0, stream, sr, sl, sv, si, parr);
  hipLaunchKernelGGL(k_chunks, dim3(B_ * H_ * NCHUNK), dim3(64), 0, stream, g, sv, si,
                     P1, P2, Zpe1, Zpe2, C1, C2, Zc1, Zc2);
  hipLaunchKernelGGL(k_scan, dim3(B_ * H_), dim3(64), 0, stream, C1, C2, Zc1, Zc2, U1, U2, Zb1, Zb2);
  hipLaunchKernelGGL(k_out, dim3(B_ * N_ * H_ / 4), dim3(256), 0, stream,
                     sl, sv, parr, P1, P2, Zpe1, Zpe2, U1, U2, Zb1, Zb2, out);
}